// Round 2
// baseline (284.214 us; speedup 1.0000x reference)
//
#include <hip/hip_runtime.h>
#include <hip/hip_bf16.h>
#include <stdint.h>
#include <stddef.h>

typedef __attribute__((ext_vector_type(8))) short short8;
typedef __attribute__((ext_vector_type(4))) float f32x4;
typedef __attribute__((ext_vector_type(4))) unsigned int u32x4;

#define DIM   512
#define NJ    17
#define NPART 5
#define NB    8192
#define KDIM  1536                  // 3 * 512
#define QROWS (NB*NPART)            // 40960
#define ROWB  (KDIM*2)              // 3072 bytes per Q/Wt row (bf16)

struct Cheb { float c[3][5][5]; };

__device__ __forceinline__ void gload_lds16(const void* g, void* l) {
  __builtin_amdgcn_global_load_lds((__attribute__((address_space(1))) void*)(g),
                                   (__attribute__((address_space(3))) void*)(l),
                                   16, 0, 0);
}

// ---------------- kernel A: pool + cheb -> Q bf16 (pre-swizzled) ----------------
__global__ __launch_bounds__(256) void pool_cheb_kernel(
    const float* __restrict__ x, __hip_bfloat16* __restrict__ Q, Cheb cb) {
  int gid = blockIdx.x * 256 + threadIdx.x;       // 8192*64 threads
  int b  = gid >> 6;
  int dc = gid & 63;                              // 8-elem d-chunk, d0 = dc*8
  int d0 = dc << 3;
  const float* xb = x + (size_t)b * (NJ * DIM) + d0;

  float pf[5][8];
#pragma unroll
  for (int p = 0; p < 5; ++p)
#pragma unroll
    for (int i = 0; i < 8; ++i) pf[p][i] = 0.f;

  constexpr int jpart[NJ] = {2,0,0,0,1,1,1,2,2,2,2,3,3,3,4,4,4};
#pragma unroll
  for (int j = 0; j < NJ; ++j) {
    const float4* s4 = reinterpret_cast<const float4*>(xb + j * DIM);
    float4 a = s4[0];
    float4 c4 = s4[1];
    int p = jpart[j];
    pf[p][0] += a.x;  pf[p][1] += a.y;  pf[p][2] += a.z;  pf[p][3] += a.w;
    pf[p][4] += c4.x; pf[p][5] += c4.y; pf[p][6] += c4.z; pf[p][7] += c4.w;
  }
  constexpr float scl[5] = {1.f/3.f, 1.f/3.f, 0.2f, 1.f/3.f, 1.f/3.f};
#pragma unroll
  for (int p = 0; p < 5; ++p)
#pragma unroll
    for (int i = 0; i < 8; ++i) pf[p][i] *= scl[p];

  char* qb = reinterpret_cast<char*>(Q);
#pragma unroll
  for (int k = 0; k < 3; ++k) {
#pragma unroll
    for (int n = 0; n < 5; ++n) {
      int row = b * 5 + n;
      alignas(16) __hip_bfloat16 o[8];
#pragma unroll
      for (int i = 0; i < 8; ++i) {
        float s = cb.c[k][n][0] * pf[0][i] + cb.c[k][n][1] * pf[1][i] +
                  cb.c[k][n][2] * pf[2][i] + cb.c[k][n][3] * pf[3][i] +
                  cb.c[k][n][4] * pf[4][i];
        o[i] = __float2bfloat16(s);
      }
      int blk = k * 8 + (dc >> 3);                // 128B K-block index (0..23)
      int swc = (dc & 7) ^ (row & 7);             // swizzled 16B chunk
      size_t off = (size_t)row * ROWB + (size_t)blk * 128 + (size_t)swc * 16;
      *reinterpret_cast<u32x4*>(qb + off) = *reinterpret_cast<const u32x4*>(o);
    }
  }
}

// ---------------- kernel A2: weight [3,512,512] f32 -> Wt[e][k*512+d] bf16 (pre-swizzled)
__global__ __launch_bounds__(256) void wt_kernel(
    const float* __restrict__ w, __hip_bfloat16* __restrict__ Wt) {
  int gid = blockIdx.x * 256 + threadIdx.x;       // 512 e * 192 chunks
  int e = gid & 511;
  int chunk = gid >> 9;                           // 0..191
  int kidx0 = chunk << 3;
  alignas(16) __hip_bfloat16 o[8];
#pragma unroll
  for (int i = 0; i < 8; ++i)
    o[i] = __float2bfloat16(w[(size_t)(kidx0 + i) * DIM + e]);
  int blk = kidx0 >> 6;
  int swc = ((kidx0 >> 3) & 7) ^ (e & 7);
  size_t off = (size_t)e * ROWB + (size_t)blk * 128 + (size_t)swc * 16;
  *reinterpret_cast<u32x4*>(reinterpret_cast<char*>(Wt) + off) =
      *reinterpret_cast<const u32x4*>(o);
}

// ---------------- kernel B: GEMM (M=40960,K=1536,N=512) + bias + scatter ------
// 128x128 tile, BK=64, 4 waves (2x2), double-buffered LDS prefetch pipeline,
// XCD-aware block swizzle (4 N-tiles of an M-tile land on one XCD's L2).
__global__ __launch_bounds__(256) void gemm_scatter_kernel(
    const __hip_bfloat16* __restrict__ Q, const __hip_bfloat16* __restrict__ Wt,
    const float* __restrict__ bias, float* __restrict__ out) {
  __shared__ __align__(16) char As[2][128 * 128];
  __shared__ __align__(16) char Bs[2][128 * 128];

  int tid  = threadIdx.x;
  int lane = tid & 63;
  int wave = tid >> 6;
  int wr = wave >> 1, wc = wave & 1;

  // XCD swizzle: nwg = 1280 = 8 * 160. orig g -> wgid = (g%8)*160 + g/8.
  // n-tile fastest within wgid => the 4 n-tiles of an m-tile run consecutively
  // on the same XCD, so the Q m-tile is fetched into that XCD's L2 once.
  int g = blockIdx.x;
  int wgid = (g & 7) * 160 + (g >> 3);
  int m0 = (wgid >> 2) * 128;
  int n0 = (wgid & 3) * 128;

  f32x4 acc[4][4] = {};

  const char* qb = reinterpret_cast<const char*>(Q);
  const char* wb = reinterpret_cast<const char*>(Wt);
  int sr = lane >> 3;                 // row within 8-row group
  int sc = (lane & 7) * 16;           // 16B chunk within 128B row-block

  // ---- stage helper: one K-step tile pair into buffer `buf` ----
  auto stage = [&](int buf, int ks) {
#pragma unroll
    for (int i = 0; i < 4; ++i) {
      int rbase = wave * 32 + i * 8;
      gload_lds16(qb + (size_t)(m0 + rbase + sr) * ROWB + (size_t)ks * 128 + sc,
                  As[buf] + rbase * 128);
      gload_lds16(wb + (size_t)(n0 + rbase + sr) * ROWB + (size_t)ks * 128 + sc,
                  Bs[buf] + rbase * 128);
    }
  };

  auto compute = [&](int buf) {
#pragma unroll
    for (int kk = 0; kk < 2; ++kk) {
      short8 af[4], bfr[4];
#pragma unroll
      for (int mi = 0; mi < 4; ++mi) {
        int r = wr * 64 + mi * 16 + (lane & 15);
        int c7 = (kk * 4 + (lane >> 4)) ^ (r & 7);
        af[mi] = *reinterpret_cast<const short8*>(As[buf] + r * 128 + c7 * 16);
      }
#pragma unroll
      for (int ni = 0; ni < 4; ++ni) {
        int r = wc * 64 + ni * 16 + (lane & 15);
        int c7 = (kk * 4 + (lane >> 4)) ^ (r & 7);
        bfr[ni] = *reinterpret_cast<const short8*>(Bs[buf] + r * 128 + c7 * 16);
      }
#pragma unroll
      for (int mi = 0; mi < 4; ++mi)
#pragma unroll
        for (int ni = 0; ni < 4; ++ni)
          acc[mi][ni] = __builtin_amdgcn_mfma_f32_16x16x32_bf16(
              af[mi], bfr[ni], acc[mi][ni], 0, 0, 0);
    }
  };

  // ---- pipelined K-loop: prefetch ks+1 while computing ks ----
  stage(0, 0);
  __syncthreads();                    // drains vmcnt -> buf0 ready
  int cur = 0;
  for (int ks = 0; ks < 23; ++ks) {
    stage(cur ^ 1, ks + 1);           // prefetch next tile (overlaps compute)
    compute(cur);
    __syncthreads();                  // drain own vmcnt (prefetch) + all reads done
    cur ^= 1;
  }
  compute(cur);                       // last tile, no prefetch

  // epilogue: bias + scatter each part row to its joints
  int colbase = n0 + wc * 64 + (lane & 15);
  float bs[4];
#pragma unroll
  for (int ni = 0; ni < 4; ++ni) bs[ni] = bias[colbase + ni * 16];

#pragma unroll
  for (int mi = 0; mi < 4; ++mi) {
#pragma unroll
    for (int j = 0; j < 4; ++j) {
      int grow = m0 + wr * 64 + mi * 16 + ((lane >> 4) << 2) + j;  // = b*5+n
      int bb = grow / 5;
      int n  = grow - bb * 5;
      unsigned mask = (n == 0) ? 0x0000Eu :
                      (n == 1) ? 0x00070u :
                      (n == 2) ? 0x00781u :
                      (n == 3) ? 0x03800u : 0x1C000u;
      float vv[4];
#pragma unroll
      for (int ni = 0; ni < 4; ++ni) vv[ni] = acc[mi][ni][j] + bs[ni];
      size_t ob = (size_t)bb * (NJ * DIM) + colbase;
      while (mask) {
        int jn = __builtin_ctz(mask);
        mask &= mask - 1;
        float* op = out + ob + (size_t)jn * DIM;
#pragma unroll
        for (int ni = 0; ni < 4; ++ni) op[ni * 16] = vv[ni];
      }
    }
  }
}

extern "C" void kernel_launch(void* const* d_in, const int* in_sizes, int n_in,
                              void* d_out, int out_size, void* d_ws, size_t ws_size,
                              hipStream_t stream) {
  const float* x    = (const float*)d_in[0];   // [8192,17,512]
  const float* w    = (const float*)d_in[1];   // [3,1,512,512]
  const float* bias = (const float*)d_in[2];   // [1,1,512]
  float* out = (float*)d_out;                  // [8192,17,512]

  // workspace: Q (40960 x 1536 bf16) then Wt (512 x 1536 bf16); needs ~127.5 MB
  __hip_bfloat16* Q  = (__hip_bfloat16*)d_ws;
  __hip_bfloat16* Wt = (__hip_bfloat16*)((char*)d_ws + (size_t)QROWS * ROWB);

  // host-side Cheb basis (K=2): T0=I, T1=L, T2=2L^2-I with L = I - rownorm(adj)
  Cheb cb;
  {
    double A[5][5] = {};
    const int e0[4] = {0, 1, 2, 2}, e1[4] = {2, 2, 3, 4};
    for (int t = 0; t < 4; ++t) { A[e0[t]][e1[t]] = 1.0; A[e1[t]][e0[t]] = 1.0; }
    for (int i = 0; i < 5; ++i) A[i][i] += 1.0;
    for (int i = 0; i < 5; ++i) {
      double rs = 0; for (int j = 0; j < 5; ++j) rs += A[i][j];
      for (int j = 0; j < 5; ++j) A[i][j] /= rs;
    }
    double L[5][5], T2[5][5];
    for (int i = 0; i < 5; ++i)
      for (int j = 0; j < 5; ++j) L[i][j] = (i == j ? 1.0 : 0.0) - A[i][j];
    for (int i = 0; i < 5; ++i)
      for (int j = 0; j < 5; ++j) {
        double s = 0; for (int m = 0; m < 5; ++m) s += L[i][m] * L[m][j];
        T2[i][j] = 2.0 * s - (i == j ? 1.0 : 0.0);
      }
    for (int i = 0; i < 5; ++i)
      for (int j = 0; j < 5; ++j) {
        cb.c[0][i][j] = (float)(i == j ? 1.0 : 0.0);
        cb.c[1][i][j] = (float)L[i][j];
        cb.c[2][i][j] = (float)T2[i][j];
      }
  }

  pool_cheb_kernel<<<(NB * 64) / 256, 256, 0, stream>>>(x, Q, cb);
  wt_kernel<<<(DIM * (KDIM / 8)) / 256, 256, 0, stream>>>(w, Wt);
  gemm_scatter_kernel<<<DIM / 128 * (QROWS / 128), 256, 0, stream>>>(Q, Wt, bias, out);
}

// Round 3
// 282.960 us; speedup vs baseline: 1.0044x; 1.0044x over previous
//
#include <hip/hip_runtime.h>
#include <hip/hip_bf16.h>
#include <stdint.h>
#include <stddef.h>

typedef __attribute__((ext_vector_type(8))) short short8;
typedef __attribute__((ext_vector_type(4))) float f32x4;
typedef __attribute__((ext_vector_type(4))) unsigned int u32x4;

#define DIM   512
#define NJ    17
#define NPART 5
#define NB    8192
#define KDIM  1536                  // 3 * 512
#define QROWS (NB*NPART)            // 40960
#define ROWB  (KDIM*2)              // 3072 bytes per Q/Wt row (bf16)

struct Cheb { float c[3][5][5]; };

__device__ __forceinline__ void gload_lds16(const void* g, void* l) {
  __builtin_amdgcn_global_load_lds((__attribute__((address_space(1))) void*)(g),
                                   (__attribute__((address_space(3))) void*)(l),
                                   16, 0, 0);
}

// ---------------- kernel A: pool + cheb -> Q bf16 (pre-swizzled) ----------------
// Q layout: row r = b*5+n (ROWB bytes per row). Within each 128B K-block
// (64 bf16), 16B chunk index is XORed with (r&7) so that a LINEAR
// global_load_lds into LDS yields the bank-conflict-free swizzled layout.
__global__ __launch_bounds__(256) void pool_cheb_kernel(
    const float* __restrict__ x, __hip_bfloat16* __restrict__ Q, Cheb cb) {
  int gid = blockIdx.x * 256 + threadIdx.x;       // 8192*64 threads
  int b  = gid >> 6;
  int dc = gid & 63;                              // 8-elem d-chunk, d0 = dc*8
  int d0 = dc << 3;
  const float* xb = x + (size_t)b * (NJ * DIM) + d0;

  float pf[5][8];
#pragma unroll
  for (int p = 0; p < 5; ++p)
#pragma unroll
    for (int i = 0; i < 8; ++i) pf[p][i] = 0.f;

  constexpr int jpart[NJ] = {2,0,0,0,1,1,1,2,2,2,2,3,3,3,4,4,4};
#pragma unroll
  for (int j = 0; j < NJ; ++j) {
    const float4* s4 = reinterpret_cast<const float4*>(xb + j * DIM);
    float4 a = s4[0];
    float4 c4 = s4[1];
    int p = jpart[j];
    pf[p][0] += a.x;  pf[p][1] += a.y;  pf[p][2] += a.z;  pf[p][3] += a.w;
    pf[p][4] += c4.x; pf[p][5] += c4.y; pf[p][6] += c4.z; pf[p][7] += c4.w;
  }
  constexpr float scl[5] = {1.f/3.f, 1.f/3.f, 0.2f, 1.f/3.f, 1.f/3.f};
#pragma unroll
  for (int p = 0; p < 5; ++p)
#pragma unroll
    for (int i = 0; i < 8; ++i) pf[p][i] *= scl[p];

  char* qb = reinterpret_cast<char*>(Q);
#pragma unroll
  for (int k = 0; k < 3; ++k) {
#pragma unroll
    for (int n = 0; n < 5; ++n) {
      int row = b * 5 + n;
      alignas(16) __hip_bfloat16 o[8];
#pragma unroll
      for (int i = 0; i < 8; ++i) {
        float s = cb.c[k][n][0] * pf[0][i] + cb.c[k][n][1] * pf[1][i] +
                  cb.c[k][n][2] * pf[2][i] + cb.c[k][n][3] * pf[3][i] +
                  cb.c[k][n][4] * pf[4][i];
        o[i] = __float2bfloat16(s);
      }
      int blk = k * 8 + (dc >> 3);                // 128B K-block index (0..23)
      int swc = (dc & 7) ^ (row & 7);             // swizzled 16B chunk
      size_t off = (size_t)row * ROWB + (size_t)blk * 128 + (size_t)swc * 16;
      *reinterpret_cast<u32x4*>(qb + off) = *reinterpret_cast<const u32x4*>(o);
    }
  }
}

// ---------------- kernel A2: weight [3,512,512] f32 -> Wt[e][k*512+d] bf16 (pre-swizzled)
__global__ __launch_bounds__(256) void wt_kernel(
    const float* __restrict__ w, __hip_bfloat16* __restrict__ Wt) {
  int gid = blockIdx.x * 256 + threadIdx.x;       // 512 e * 192 chunks
  int e = gid & 511;
  int chunk = gid >> 9;                           // 0..191
  int kidx0 = chunk << 3;
  alignas(16) __hip_bfloat16 o[8];
#pragma unroll
  for (int i = 0; i < 8; ++i)
    o[i] = __float2bfloat16(w[(size_t)(kidx0 + i) * DIM + e]);
  int blk = kidx0 >> 6;
  int swc = ((kidx0 >> 3) & 7) ^ (e & 7);
  size_t off = (size_t)e * ROWB + (size_t)blk * 128 + (size_t)swc * 16;
  *reinterpret_cast<u32x4*>(reinterpret_cast<char*>(Wt) + off) =
      *reinterpret_cast<const u32x4*>(o);
}

// ---------------- kernel B: GEMM (M=40960,K=1536,N=512) + bias + scatter ------
// 128x128 tile, BK=64, 4 waves (2x2), SINGLE-buffered LDS (32 KB -> 5 blocks/CU,
// implicit cross-block overlap), XCD-aware block swizzle for L2 locality.
__global__ __launch_bounds__(256) void gemm_scatter_kernel(
    const __hip_bfloat16* __restrict__ Q, const __hip_bfloat16* __restrict__ Wt,
    const float* __restrict__ bias, float* __restrict__ out) {
  __shared__ __align__(16) char As[128 * 128];    // 128 rows x 64 bf16 (swizzled)
  __shared__ __align__(16) char Bs[128 * 128];

  int tid  = threadIdx.x;
  int lane = tid & 63;
  int wave = tid >> 6;
  int wr = wave >> 1, wc = wave & 1;

  // XCD swizzle: nwg = 1280 = 8 * 160. orig g -> wgid = (g%8)*160 + g/8.
  // n-tile fastest within wgid => the 4 n-tiles of an m-tile run consecutively
  // on the same XCD, so the Q m-tile is fetched into that XCD's L2 once.
  int g = blockIdx.x;
  int wgid = (g & 7) * 160 + (g >> 3);
  int m0 = (wgid >> 2) * 128;
  int n0 = (wgid & 3) * 128;

  f32x4 acc[4][4] = {};

  const char* qb = reinterpret_cast<const char*>(Q);
  const char* wb = reinterpret_cast<const char*>(Wt);
  int sr = lane >> 3;                 // row within 8-row group
  int sc = (lane & 7) * 16;           // 16B chunk within 128B row-block

  for (int ks = 0; ks < 24; ++ks) {
    // stage A and B tiles: each wave stages 32 rows of each (4 issues x 8 rows)
#pragma unroll
    for (int i = 0; i < 4; ++i) {
      int rbase = wave * 32 + i * 8;
      gload_lds16(qb + (size_t)(m0 + rbase + sr) * ROWB + (size_t)ks * 128 + sc,
                  As + rbase * 128);
      gload_lds16(wb + (size_t)(n0 + rbase + sr) * ROWB + (size_t)ks * 128 + sc,
                  Bs + rbase * 128);
    }
    __syncthreads();   // drains vmcnt -> staged data visible

#pragma unroll
    for (int kk = 0; kk < 2; ++kk) {
      short8 af[4], bfr[4];
#pragma unroll
      for (int mi = 0; mi < 4; ++mi) {
        int r = wr * 64 + mi * 16 + (lane & 15);
        int c7 = (kk * 4 + (lane >> 4)) ^ (r & 7);
        af[mi] = *reinterpret_cast<const short8*>(As + r * 128 + c7 * 16);
      }
#pragma unroll
      for (int ni = 0; ni < 4; ++ni) {
        int r = wc * 64 + ni * 16 + (lane & 15);
        int c7 = (kk * 4 + (lane >> 4)) ^ (r & 7);
        bfr[ni] = *reinterpret_cast<const short8*>(Bs + r * 128 + c7 * 16);
      }
#pragma unroll
      for (int mi = 0; mi < 4; ++mi)
#pragma unroll
        for (int ni = 0; ni < 4; ++ni)
          acc[mi][ni] = __builtin_amdgcn_mfma_f32_16x16x32_bf16(
              af[mi], bfr[ni], acc[mi][ni], 0, 0, 0);
    }
    __syncthreads();   // all reads done before next stage overwrites
  }

  // epilogue: bias + scatter each part row to its joints
  int colbase = n0 + wc * 64 + (lane & 15);
  float bs[4];
#pragma unroll
  for (int ni = 0; ni < 4; ++ni) bs[ni] = bias[colbase + ni * 16];

#pragma unroll
  for (int mi = 0; mi < 4; ++mi) {
#pragma unroll
    for (int j = 0; j < 4; ++j) {
      int grow = m0 + wr * 64 + mi * 16 + ((lane >> 4) << 2) + j;  // = b*5+n
      int bb = grow / 5;
      int n  = grow - bb * 5;
      unsigned mask = (n == 0) ? 0x0000Eu :
                      (n == 1) ? 0x00070u :
                      (n == 2) ? 0x00781u :
                      (n == 3) ? 0x03800u : 0x1C000u;
      float vv[4];
#pragma unroll
      for (int ni = 0; ni < 4; ++ni) vv[ni] = acc[mi][ni][j] + bs[ni];
      size_t ob = (size_t)bb * (NJ * DIM) + colbase;
      while (mask) {
        int jn = __builtin_ctz(mask);
        mask &= mask - 1;
        float* op = out + ob + (size_t)jn * DIM;
#pragma unroll
        for (int ni = 0; ni < 4; ++ni) op[ni * 16] = vv[ni];
      }
    }
  }
}

extern "C" void kernel_launch(void* const* d_in, const int* in_sizes, int n_in,
                              void* d_out, int out_size, void* d_ws, size_t ws_size,
                              hipStream_t stream) {
  const float* x    = (const float*)d_in[0];   // [8192,17,512]
  const float* w    = (const float*)d_in[1];   // [3,1,512,512]
  const float* bias = (const float*)d_in[2];   // [1,1,512]
  float* out = (float*)d_out;                  // [8192,17,512]

  // workspace: Q (40960 x 1536 bf16) then Wt (512 x 1536 bf16); needs ~127.5 MB
  __hip_bfloat16* Q  = (__hip_bfloat16*)d_ws;
  __hip_bfloat16* Wt = (__hip_bfloat16*)((char*)d_ws + (size_t)QROWS * ROWB);

  // host-side Cheb basis (K=2): T0=I, T1=L, T2=2L^2-I with L = I - rownorm(adj)
  Cheb cb;
  {
    double A[5][5] = {};
    const int e0[4] = {0, 1, 2, 2}, e1[4] = {2, 2, 3, 4};
    for (int t = 0; t < 4; ++t) { A[e0[t]][e1[t]] = 1.0; A[e1[t]][e0[t]] = 1.0; }
    for (int i = 0; i < 5; ++i) A[i][i] += 1.0;
    for (int i = 0; i < 5; ++i) {
      double rs = 0; for (int j = 0; j < 5; ++j) rs += A[i][j];
      for (int j = 0; j < 5; ++j) A[i][j] /= rs;
    }
    double L[5][5], T2[5][5];
    for (int i = 0; i < 5; ++i)
      for (int j = 0; j < 5; ++j) L[i][j] = (i == j ? 1.0 : 0.0) - A[i][j];
    for (int i = 0; i < 5; ++i)
      for (int j = 0; j < 5; ++j) {
        double s = 0; for (int m = 0; m < 5; ++m) s += L[i][m] * L[m][j];
        T2[i][j] = 2.0 * s - (i == j ? 1.0 : 0.0);
      }
    for (int i = 0; i < 5; ++i)
      for (int j = 0; j < 5; ++j) {
        cb.c[0][i][j] = (float)(i == j ? 1.0 : 0.0);
        cb.c[1][i][j] = (float)L[i][j];
        cb.c[2][i][j] = (float)T2[i][j];
      }
  }

  pool_cheb_kernel<<<(NB * 64) / 256, 256, 0, stream>>>(x, Q, cb);
  wt_kernel<<<(DIM * (KDIM / 8)) / 256, 256, 0, stream>>>(w, Wt);
  gemm_scatter_kernel<<<DIM / 128 * (QROWS / 128), 256, 0, stream>>>(Q, Wt, bias, out);
}

// Round 4
// 273.760 us; speedup vs baseline: 1.0382x; 1.0336x over previous
//
#include <hip/hip_runtime.h>
#include <hip/hip_bf16.h>
#include <stdint.h>
#include <stddef.h>

typedef __attribute__((ext_vector_type(8))) short short8;
typedef __attribute__((ext_vector_type(4))) float f32x4;
typedef __attribute__((ext_vector_type(4))) unsigned int u32x4;

#define DIM   512
#define NJ    17
#define NPART 5
#define NB    8192
#define KDIM  1536                  // 3 * 512
#define QROWS (NB*NPART)            // 40960
#define ROWB  (KDIM*2)              // 3072 bytes per Q/Wt row (bf16)

struct Cheb { float c[3][5][5]; };

__device__ __forceinline__ void gload_lds16(const void* g, void* l) {
  __builtin_amdgcn_global_load_lds((__attribute__((address_space(1))) void*)(g),
                                   (__attribute__((address_space(3))) void*)(l),
                                   16, 0, 0);
}

// ---------------- kernel A: pool + cheb -> Q bf16 (pre-swizzled) ----------------
// Q layout: row r = b*5+n (ROWB bytes per row). Within each 128B K-block
// (64 bf16), 16B chunk index is XORed with (r&7) so that a LINEAR
// global_load_lds into LDS yields the bank-conflict-free swizzled layout.
__global__ __launch_bounds__(256) void pool_cheb_kernel(
    const float* __restrict__ x, __hip_bfloat16* __restrict__ Q, Cheb cb) {
  int gid = blockIdx.x * 256 + threadIdx.x;       // 8192*64 threads
  int b  = gid >> 6;
  int dc = gid & 63;                              // 8-elem d-chunk, d0 = dc*8
  int d0 = dc << 3;
  const float* xb = x + (size_t)b * (NJ * DIM) + d0;

  float pf[5][8];
#pragma unroll
  for (int p = 0; p < 5; ++p)
#pragma unroll
    for (int i = 0; i < 8; ++i) pf[p][i] = 0.f;

  constexpr int jpart[NJ] = {2,0,0,0,1,1,1,2,2,2,2,3,3,3,4,4,4};
#pragma unroll
  for (int j = 0; j < NJ; ++j) {
    const float4* s4 = reinterpret_cast<const float4*>(xb + j * DIM);
    float4 a = s4[0];
    float4 c4 = s4[1];
    int p = jpart[j];
    pf[p][0] += a.x;  pf[p][1] += a.y;  pf[p][2] += a.z;  pf[p][3] += a.w;
    pf[p][4] += c4.x; pf[p][5] += c4.y; pf[p][6] += c4.z; pf[p][7] += c4.w;
  }
  constexpr float scl[5] = {1.f/3.f, 1.f/3.f, 0.2f, 1.f/3.f, 1.f/3.f};
#pragma unroll
  for (int p = 0; p < 5; ++p)
#pragma unroll
    for (int i = 0; i < 8; ++i) pf[p][i] *= scl[p];

  char* qb = reinterpret_cast<char*>(Q);
#pragma unroll
  for (int k = 0; k < 3; ++k) {
#pragma unroll
    for (int n = 0; n < 5; ++n) {
      int row = b * 5 + n;
      alignas(16) __hip_bfloat16 o[8];
#pragma unroll
      for (int i = 0; i < 8; ++i) {
        float s = cb.c[k][n][0] * pf[0][i] + cb.c[k][n][1] * pf[1][i] +
                  cb.c[k][n][2] * pf[2][i] + cb.c[k][n][3] * pf[3][i] +
                  cb.c[k][n][4] * pf[4][i];
        o[i] = __float2bfloat16(s);
      }
      int blk = k * 8 + (dc >> 3);                // 128B K-block index (0..23)
      int swc = (dc & 7) ^ (row & 7);             // swizzled 16B chunk
      size_t off = (size_t)row * ROWB + (size_t)blk * 128 + (size_t)swc * 16;
      *reinterpret_cast<u32x4*>(qb + off) = *reinterpret_cast<const u32x4*>(o);
    }
  }
}

// ---------------- kernel A2: weight [3,512,512] f32 -> Wt[e][k*512+d] bf16 (pre-swizzled)
__global__ __launch_bounds__(256) void wt_kernel(
    const float* __restrict__ w, __hip_bfloat16* __restrict__ Wt) {
  int gid = blockIdx.x * 256 + threadIdx.x;       // 512 e * 192 chunks
  int e = gid & 511;
  int chunk = gid >> 9;                           // 0..191
  int kidx0 = chunk << 3;
  alignas(16) __hip_bfloat16 o[8];
#pragma unroll
  for (int i = 0; i < 8; ++i)
    o[i] = __float2bfloat16(w[(size_t)(kidx0 + i) * DIM + e]);
  int blk = kidx0 >> 6;
  int swc = ((kidx0 >> 3) & 7) ^ (e & 7);
  size_t off = (size_t)e * ROWB + (size_t)blk * 128 + (size_t)swc * 16;
  *reinterpret_cast<u32x4*>(reinterpret_cast<char*>(Wt) + off) =
      *reinterpret_cast<const u32x4*>(o);
}

// ---------------- kernel B: GEMM (M=40960,K=1536,N=512) + bias + scatter ------
// 128x128 tile, BK=64, 4 waves (2x2), single-buffered 32KB LDS, natural block
// order (XCD swizzle measured -15us: inputs are L3-resident, not HBM-read-bound).
// Epilogue stages each wave's 64x64 f32 tile through a private LDS slice to
// emit coalesced float4 scatter stores (68/thread) instead of 272 scalar.
__global__ __launch_bounds__(256) void gemm_scatter_kernel(
    const __hip_bfloat16* __restrict__ Q, const __hip_bfloat16* __restrict__ Wt,
    const float* __restrict__ bias, float* __restrict__ out) {
  __shared__ __align__(16) char LDSbuf[32768];
  char* As = LDSbuf;                 // 128 rows x 64 bf16 (swizzled) = 16 KB
  char* Bs = LDSbuf + 16384;

  int tid  = threadIdx.x;
  int lane = tid & 63;
  int wave = tid >> 6;
  int wr = wave >> 1, wc = wave & 1;
  int m0 = blockIdx.y * 128;
  int n0 = blockIdx.x * 128;

  f32x4 acc[4][4] = {};

  const char* qb = reinterpret_cast<const char*>(Q);
  const char* wb = reinterpret_cast<const char*>(Wt);
  int sr = lane >> 3;                 // row within 8-row group
  int sc = (lane & 7) * 16;           // 16B chunk within 128B row-block

  for (int ks = 0; ks < 24; ++ks) {
    // stage A and B tiles: each wave stages 32 rows of each (4 issues x 8 rows)
#pragma unroll
    for (int i = 0; i < 4; ++i) {
      int rbase = wave * 32 + i * 8;
      gload_lds16(qb + (size_t)(m0 + rbase + sr) * ROWB + (size_t)ks * 128 + sc,
                  As + rbase * 128);
      gload_lds16(wb + (size_t)(n0 + rbase + sr) * ROWB + (size_t)ks * 128 + sc,
                  Bs + rbase * 128);
    }
    __syncthreads();   // drains vmcnt -> staged data visible

#pragma unroll
    for (int kk = 0; kk < 2; ++kk) {
      short8 af[4], bfr[4];
#pragma unroll
      for (int mi = 0; mi < 4; ++mi) {
        int r = wr * 64 + mi * 16 + (lane & 15);
        int c7 = (kk * 4 + (lane >> 4)) ^ (r & 7);
        af[mi] = *reinterpret_cast<const short8*>(As + r * 128 + c7 * 16);
      }
#pragma unroll
      for (int ni = 0; ni < 4; ++ni) {
        int r = wc * 64 + ni * 16 + (lane & 15);
        int c7 = (kk * 4 + (lane >> 4)) ^ (r & 7);
        bfr[ni] = *reinterpret_cast<const short8*>(Bs + r * 128 + c7 * 16);
      }
#pragma unroll
      for (int mi = 0; mi < 4; ++mi)
#pragma unroll
        for (int ni = 0; ni < 4; ++ni)
          acc[mi][ni] = __builtin_amdgcn_mfma_f32_16x16x32_bf16(
              af[mi], bfr[ni], acc[mi][ni], 0, 0, 0);
    }
    __syncthreads();   // all reads done before next stage overwrites
  }

  // ---- epilogue: bias + LDS transpose-stage + vectorized scatter ----
  // Each wave uses a PRIVATE 4352B slice (16 rows x 68 f32, stride 68 keeps
  // bank aliasing <=2-way = free). Wave-synchronous: ds_write -> ds_read needs
  // only lgkmcnt (compiler-inserted), no barriers.
  int colbase = n0 + wc * 64 + (lane & 15);
  float bs[4];
#pragma unroll
  for (int ni = 0; ni < 4; ++ni) bs[ni] = bias[colbase + ni * 16];

  char* eb = LDSbuf + wave * 4352;
  int g4 = lane >> 4;                // 0..3
  int cc = lane & 15;                // 0..15

#pragma unroll
  for (int mi = 0; mi < 4; ++mi) {
    // write 16 rows x 64 cols f32 with bias added
#pragma unroll
    for (int ni = 0; ni < 4; ++ni)
#pragma unroll
      for (int j = 0; j < 4; ++j)
        *reinterpret_cast<float*>(
            eb + (((g4 * 4 + j) * 68 + ni * 16 + cc) << 2)) =
            acc[mi][ni][j] + bs[ni];

    // read back coalesced: 4 x ds_read_b128, lane -> (row t*4+g4, col cc*4)
#pragma unroll
    for (int t = 0; t < 4; ++t) {
      float4 v4 = *reinterpret_cast<const float4*>(
          eb + ((((t * 4 + g4) * 68) + cc * 4) << 2));
      int R4 = m0 + wr * 64 + mi * 16 + t * 4 + g4;   // part row = b*5+n
      unsigned bb = (unsigned)R4 / 5u;
      int n = R4 - (int)bb * 5;
      unsigned mask = (n == 0) ? 0x0000Eu :
                      (n == 1) ? 0x00070u :
                      (n == 2) ? 0x00781u :
                      (n == 3) ? 0x03800u : 0x1C000u;
      float* op = out + (size_t)bb * (NJ * DIM) + (n0 + wc * 64 + cc * 4);
      while (mask) {
        int jn = __builtin_ctz(mask);
        mask &= mask - 1;
        *reinterpret_cast<float4*>(op + jn * DIM) = v4;
      }
    }
  }
}

extern "C" void kernel_launch(void* const* d_in, const int* in_sizes, int n_in,
                              void* d_out, int out_size, void* d_ws, size_t ws_size,
                              hipStream_t stream) {
  const float* x    = (const float*)d_in[0];   // [8192,17,512]
  const float* w    = (const float*)d_in[1];   // [3,1,512,512]
  const float* bias = (const float*)d_in[2];   // [1,1,512]
  float* out = (float*)d_out;                  // [8192,17,512]

  // workspace: Q (40960 x 1536 bf16) then Wt (512 x 1536 bf16); needs ~127.5 MB
  __hip_bfloat16* Q  = (__hip_bfloat16*)d_ws;
  __hip_bfloat16* Wt = (__hip_bfloat16*)((char*)d_ws + (size_t)QROWS * ROWB);

  // host-side Cheb basis (K=2): T0=I, T1=L, T2=2L^2-I with L = I - rownorm(adj)
  Cheb cb;
  {
    double A[5][5] = {};
    const int e0[4] = {0, 1, 2, 2}, e1[4] = {2, 2, 3, 4};
    for (int t = 0; t < 4; ++t) { A[e0[t]][e1[t]] = 1.0; A[e1[t]][e0[t]] = 1.0; }
    for (int i = 0; i < 5; ++i) A[i][i] += 1.0;
    for (int i = 0; i < 5; ++i) {
      double rs = 0; for (int j = 0; j < 5; ++j) rs += A[i][j];
      for (int j = 0; j < 5; ++j) A[i][j] /= rs;
    }
    double L[5][5], T2[5][5];
    for (int i = 0; i < 5; ++i)
      for (int j = 0; j < 5; ++j) L[i][j] = (i == j ? 1.0 : 0.0) - A[i][j];
    for (int i = 0; i < 5; ++i)
      for (int j = 0; j < 5; ++j) {
        double s = 0; for (int m = 0; m < 5; ++m) s += L[i][m] * L[m][j];
        T2[i][j] = 2.0 * s - (i == j ? 1.0 : 0.0);
      }
    for (int i = 0; i < 5; ++i)
      for (int j = 0; j < 5; ++j) {
        cb.c[0][i][j] = (float)(i == j ? 1.0 : 0.0);
        cb.c[1][i][j] = (float)L[i][j];
        cb.c[2][i][j] = (float)T2[i][j];
      }
  }

  pool_cheb_kernel<<<(NB * 64) / 256, 256, 0, stream>>>(x, Q, cb);
  wt_kernel<<<(DIM * (KDIM / 8)) / 256, 256, 0, stream>>>(w, Wt);
  gemm_scatter_kernel<<<dim3(DIM / 128, QROWS / 128), 256, 0, stream>>>(Q, Wt, bias, out);
}